// Round 2
// baseline (11124.124 us; speedup 1.0000x reference)
//
#include <hip/hip_runtime.h>
#include <hip/hip_bf16.h>
#include <math.h>

#define DEV __device__ __forceinline__

typedef __bf16 bf16;
typedef bf16 bf16x8 __attribute__((ext_vector_type(8)));
typedef float f32x4 __attribute__((ext_vector_type(4)));

constexpr int N_NODES = 50000;
constexpr int N_EDGES = 800000;
constexpr int H = 128;

DEV float fsilu(float x) { return x / (1.f + __expf(-x)); }
DEV float fsigmoid(float x) { return 1.f / (1.f + __expf(-x)); }

// ---------------- small prep kernels ----------------

// dst[n*KP + k] = (k < K) ? src[k*Nf + n] : 0   (weights -> bf16, transposed, K-padded)
__global__ void transpose_pad_kernel(bf16* __restrict__ dst, const float* __restrict__ src,
                                     int K, int Nf, int KP) {
    int idx = blockIdx.x * 256 + threadIdx.x;
    if (idx >= Nf * KP) return;
    int n = idx / KP, k = idx - n * KP;
    dst[idx] = (k < K) ? (bf16)src[k * Nf + n] : (bf16)0.f;
}

__global__ void h_init_kernel(const float* __restrict__ h, float* __restrict__ h_cur,
                              bf16* __restrict__ h_bf, int n) {
    int i = blockIdx.x * 256 + threadIdx.x;
    if (i < n) { float v = h[i]; h_cur[i] = v; h_bf[i] = (bf16)v; }
}

// radial + edge_attr -> bf16 [E][2]
__global__ void ea_kernel(const float* __restrict__ x, const int* __restrict__ ei,
                          const float* __restrict__ eattr, bf16* __restrict__ ea_bf) {
    int e = blockIdx.x * 256 + threadIdx.x;
    if (e >= N_EDGES) return;
    int r = ei[e], c = ei[N_EDGES + e];
    float dx = x[r * 3 + 0] - x[c * 3 + 0];
    float dy = x[r * 3 + 1] - x[c * 3 + 1];
    float dz = x[r * 3 + 2] - x[c * 3 + 2];
    float radial = dx * dx + dy * dy + dz * dz;
    ea_bf[e * 2 + 0] = (bf16)radial;
    ea_bf[e * 2 + 1] = (bf16)eattr[e];
}

__global__ void out_h_kernel(const float* __restrict__ h_cur, const float* __restrict__ nmask,
                             float* __restrict__ out) {
    int i = blockIdx.x * 256 + threadIdx.x;
    if (i < N_NODES * H) out[i] = h_cur[i] * nmask[i >> 7];
}

__global__ void out_x_kernel(const float* __restrict__ x, const float* __restrict__ aggx,
                             const float* __restrict__ nmask, float* __restrict__ out) {
    int i = blockIdx.x * 256 + threadIdx.x;
    if (i < N_NODES * 3) out[i] = (x[i] + aggx[i] * 0.01f) * nmask[i / 3];
}

// ---------------- MFMA helpers ----------------
// Wave computes a 64(edge-rows) x 32(features) strip: 4 edge-row tiles x 2 feature tiles.
// A layout (16x16x32 bf16): lane holds A[lane&15][(lane>>4)*8 + i]
// B layout:                 lane holds B[(lane>>4)*8 + i][lane&15]
// C/D layout (HW-verified): col = lane&15, row = (lane>>4)*4 + reg

template <int KCHUNKS, int ASTRIDE, int BSTRIDE>
DEV void wave_gemm(const bf16* A_lds, const bf16* __restrict__ Bt,
                   f32x4 (&acc)[4][2], int lr, int lg, int wv) {
#pragma unroll
    for (int kk = 0; kk < KCHUNKS; ++kk) {
        int ko = kk * 32 + lg * 8;
        bf16x8 a[4], b[2];
#pragma unroll
        for (int er = 0; er < 4; ++er)
            a[er] = *(const bf16x8*)(A_lds + (er * 16 + lr) * ASTRIDE + ko);
#pragma unroll
        for (int j = 0; j < 2; ++j)
            b[j] = *(const bf16x8*)(Bt + (size_t)((wv * 2 + j) * 16 + lr) * BSTRIDE + ko);
#pragma unroll
        for (int er = 0; er < 4; ++er)
#pragma unroll
            for (int j = 0; j < 2; ++j)
                acc[er][j] = __builtin_amdgcn_mfma_f32_16x16x32_bf16(a[er], b[j], acc[er][j], 0, 0, 0);
    }
}

// silu(acc + bias[feat]) -> bf16 LDS tile [64][OSTRIDE]
DEV void epi_silu_store(const f32x4 (&acc)[4][2], const float* __restrict__ bias,
                        bf16* out_lds, int OSTRIDE, int lr, int lg, int wv) {
    float b0 = bias[(wv * 2 + 0) * 16 + lr];
    float b1 = bias[(wv * 2 + 1) * 16 + lr];
#pragma unroll
    for (int er = 0; er < 4; ++er) {
#pragma unroll
        for (int j = 0; j < 2; ++j) {
            float bb = j ? b1 : b0;
            int fcol = (wv * 2 + j) * 16 + lr;
#pragma unroll
            for (int r = 0; r < 4; ++r) {
                int rrow = er * 16 + lg * 4 + r;
                out_lds[rrow * OSTRIDE + fcol] = (bf16)fsilu(acc[er][j][r] + bb);
            }
        }
    }
}

// ---------------- edge / coord kernel ----------------
// MODE 0: GCL edge MLP + attention + atomic agg into agg[N][128]
// MODE 1: coord MLP -> phi, trans = coord_diff*phi*mask, atomic into aggx[N][3]
template <int MODE>
__global__ __launch_bounds__(256, 2) void edge_kernel(
    const bf16* __restrict__ h_bf, const bf16* __restrict__ ea_bf,
    const int* __restrict__ ei, const float* __restrict__ emask,
    const bf16* __restrict__ w1t, const float* __restrict__ b1,
    const bf16* __restrict__ w2t, const float* __restrict__ b2,
    const float* __restrict__ avec, const float* __restrict__ abias,
    const float* __restrict__ xg, float* __restrict__ aggout) {
    constexpr int SR1 = 296;  // einp row stride (bf16): 592B, 16B-mult, 2-way bank alias only
    constexpr int TR = 136;   // t1/mij row stride: 272B, 16B-mult, 2-way alias
    __shared__ __align__(16) bf16 einp[64 * SR1];  // also reused as mij [64][TR]
    __shared__ __align__(16) bf16 t1[64 * TR];
    __shared__ int row_l[64];
    __shared__ int col_l[64];
    __shared__ float em_l[64];

    int t = threadIdx.x, lane = t & 63, wv = t >> 6;
    int lr = lane & 15, lg = lane >> 4;
    int ebase = blockIdx.x * 64;

    if (t < 64) {
        int e = ebase + t;
        row_l[t] = ei[e];
        col_l[t] = ei[N_EDGES + e];
        em_l[t] = emask[e];
        einp[t * SR1 + 256] = ea_bf[e * 2 + 0];
        einp[t * SR1 + 257] = ea_bf[e * 2 + 1];
#pragma unroll
        for (int k = 258; k < 288; ++k) einp[t * SR1 + k] = (bf16)0.f;
    }
    {   // gather h[row] | h[col] into einp, 4 threads per edge, 16B vector moves
        int el = t >> 2, q = t & 3;
        int e = ebase + el;
        int rr = ei[e], cc = ei[N_EDGES + e];
        const bf16* hr = h_bf + (size_t)rr * H;
        const bf16* hc = h_bf + (size_t)cc * H;
        bf16* dst = einp + el * SR1;
#pragma unroll
        for (int pp = 0; pp < 4; ++pp) {
            int ch = pp * 4 + q;
            *(bf16x8*)(dst + ch * 8) = *(const bf16x8*)(hr + ch * 8);
            *(bf16x8*)(dst + 128 + ch * 8) = *(const bf16x8*)(hc + ch * 8);
        }
    }
    __syncthreads();

    f32x4 acc[4][2];
#pragma unroll
    for (int er = 0; er < 4; ++er)
#pragma unroll
        for (int j = 0; j < 2; ++j) acc[er][j] = (f32x4)0.f;
    wave_gemm<9, SR1, 288>(einp, w1t, acc, lr, lg, wv);
    epi_silu_store(acc, b1, t1, TR, lr, lg, wv);
    __syncthreads();  // t1 ready; also: all waves done reading einp

    f32x4 acc2[4][2];
#pragma unroll
    for (int er = 0; er < 4; ++er)
#pragma unroll
        for (int j = 0; j < 2; ++j) acc2[er][j] = (f32x4)0.f;
    wave_gemm<4, TR, 128>(t1, w2t, acc2, lr, lg, wv);

    bf16* mij = einp;  // reuse einp region (all GEMM1 reads completed)
    epi_silu_store(acc2, b2, mij, TR, lr, lg, wv);
    __syncthreads();

    // per-edge dot over 128 features: 4 threads/edge, 32 feats each, shfl reduce
    int el = t >> 2, q = t & 3;
    const bf16* mrow = mij + el * TR + q * 32;
    float part = 0.f;
#pragma unroll
    for (int c = 0; c < 4; ++c) {
        bf16x8 v = *(const bf16x8*)(mrow + c * 8);
#pragma unroll
        for (int jj = 0; jj < 8; ++jj) part += (float)v[jj] * avec[q * 32 + c * 8 + jj];
    }
    part += __shfl_xor(part, 1);
    part += __shfl_xor(part, 2);

    if (MODE == 0) {
        float att = fsigmoid(part + abias[0]);
        float scale = att * em_l[el];
        float* adst = aggout + (size_t)row_l[el] * H + q * 32;
#pragma unroll
        for (int c = 0; c < 4; ++c) {
            bf16x8 v = *(const bf16x8*)(mrow + c * 8);
#pragma unroll
            for (int jj = 0; jj < 8; ++jj)
                atomicAdd(adst + c * 8 + jj, (float)v[jj] * scale);
        }
    } else {
        if (q == 0) {
            int rr = row_l[el], cc = col_l[el];
            float dx = xg[rr * 3 + 0] - xg[cc * 3 + 0];
            float dy = xg[rr * 3 + 1] - xg[cc * 3 + 1];
            float dz = xg[rr * 3 + 2] - xg[cc * 3 + 2];
            float radial = dx * dx + dy * dy + dz * dz;
            float inv = 1.f / (sqrtf(radial + 1e-8f) + 1.f);
            float s = part * em_l[el] * inv;
            atomicAdd(aggout + rr * 3 + 0, dx * s);
            atomicAdd(aggout + rr * 3 + 1, dy * s);
            atomicAdd(aggout + rr * 3 + 2, dz * s);
        }
    }
}

// ---------------- node MLP kernel ----------------
__global__ __launch_bounds__(256, 2) void node_kernel(
    float* __restrict__ h_cur, bf16* __restrict__ h_bf, const float* __restrict__ agg,
    const bf16* __restrict__ w1t, const float* __restrict__ b1,
    const bf16* __restrict__ w2t, const float* __restrict__ b2,
    const float* __restrict__ nmask) {
    constexpr int SRN = 264;  // ninp row stride: 528B
    constexpr int TRN = 136;
    __shared__ __align__(16) bf16 ninp[64 * SRN];
    __shared__ __align__(16) bf16 t1[64 * TRN];

    int t = threadIdx.x, lane = t & 63, wv = t >> 6;
    int lr = lane & 15, lg = lane >> 4;
    int nbase = blockIdx.x * 64;

    {   // stage ninp = [bf16(h), bf16(agg*0.01)]
        int nl = t >> 2, q = t & 3;
        int node = nbase + nl;
        bf16* dst = ninp + nl * SRN;
        if (node < N_NODES) {
            const float4* hr = (const float4*)(h_cur + (size_t)node * H);
            const float4* ar = (const float4*)(agg + (size_t)node * H);
#pragma unroll
            for (int pp = 0; pp < 8; ++pp) {
                int ch = pp * 4 + q;
                float4 v = hr[ch];
                dst[ch * 4 + 0] = (bf16)v.x; dst[ch * 4 + 1] = (bf16)v.y;
                dst[ch * 4 + 2] = (bf16)v.z; dst[ch * 4 + 3] = (bf16)v.w;
            }
#pragma unroll
            for (int pp = 0; pp < 8; ++pp) {
                int ch = pp * 4 + q;
                float4 v = ar[ch];
                dst[128 + ch * 4 + 0] = (bf16)(v.x * 0.01f);
                dst[128 + ch * 4 + 1] = (bf16)(v.y * 0.01f);
                dst[128 + ch * 4 + 2] = (bf16)(v.z * 0.01f);
                dst[128 + ch * 4 + 3] = (bf16)(v.w * 0.01f);
            }
        } else {
#pragma unroll
            for (int pp = 0; pp < 8; ++pp) {
                int ch = pp * 4 + q;
#pragma unroll
                for (int k = 0; k < 4; ++k) {
                    dst[ch * 4 + k] = (bf16)0.f;
                    dst[128 + ch * 4 + k] = (bf16)0.f;
                }
            }
        }
    }
    __syncthreads();

    f32x4 acc[4][2];
#pragma unroll
    for (int er = 0; er < 4; ++er)
#pragma unroll
        for (int j = 0; j < 2; ++j) acc[er][j] = (f32x4)0.f;
    wave_gemm<8, SRN, 256>(ninp, w1t, acc, lr, lg, wv);
    epi_silu_store(acc, b1, t1, TRN, lr, lg, wv);
    __syncthreads();

    f32x4 acc2[4][2];
#pragma unroll
    for (int er = 0; er < 4; ++er)
#pragma unroll
        for (int j = 0; j < 2; ++j) acc2[er][j] = (f32x4)0.f;
    wave_gemm<4, TRN, 128>(t1, w2t, acc2, lr, lg, wv);

    float bb0 = b2[(wv * 2 + 0) * 16 + lr];
    float bb1 = b2[(wv * 2 + 1) * 16 + lr];
#pragma unroll
    for (int er = 0; er < 4; ++er) {
#pragma unroll
        for (int j = 0; j < 2; ++j) {
            float bb = j ? bb1 : bb0;
            int feat = (wv * 2 + j) * 16 + lr;
#pragma unroll
            for (int r = 0; r < 4; ++r) {
                int node = nbase + er * 16 + lg * 4 + r;
                if (node < N_NODES) {
                    size_t idx = (size_t)node * H + feat;
                    float nm = nmask[node];
                    float v = (h_cur[idx] + acc2[er][j][r] + bb) * nm;  // residual in fp32
                    h_cur[idx] = v;
                    h_bf[idx] = (bf16)v;
                }
            }
        }
    }
}

// ---------------- launch ----------------
extern "C" void kernel_launch(void* const* d_in, const int* in_sizes, int n_in,
                              void* d_out, int out_size, void* d_ws, size_t ws_size,
                              hipStream_t stream) {
    (void)in_sizes; (void)n_in; (void)out_size; (void)ws_size;
    const float* h_in  = (const float*)d_in[0];
    const float* x_in  = (const float*)d_in[1];
    const int*   ei    = (const int*)d_in[2];
    const float* eattr = (const float*)d_in[3];
    const float* nmask = (const float*)d_in[4];
    const float* emask = (const float*)d_in[5];
    const float* e_w1  = (const float*)d_in[6];
    const float* e_b1  = (const float*)d_in[7];
    const float* e_w2  = (const float*)d_in[8];
    const float* e_b2  = (const float*)d_in[9];
    const float* a_w   = (const float*)d_in[10];
    const float* a_b   = (const float*)d_in[11];
    const float* n_w1  = (const float*)d_in[12];
    const float* n_b1  = (const float*)d_in[13];
    const float* n_w2  = (const float*)d_in[14];
    const float* n_b2  = (const float*)d_in[15];
    const float* c_w1  = (const float*)d_in[16];
    const float* c_b1  = (const float*)d_in[17];
    const float* c_w2  = (const float*)d_in[18];
    const float* c_b2  = (const float*)d_in[19];
    const float* c_w3  = (const float*)d_in[20];
    float* out = (float*)d_out;

    char* p = (char*)d_ws;
    auto alloc = [&](size_t bytes) { char* r = p; p += (bytes + 255) & ~(size_t)255; return r; };
    float* h_cur = (float*)alloc((size_t)N_NODES * H * 4);
    bf16*  h_bf  = (bf16*) alloc((size_t)N_NODES * H * 2);
    float* agg   = (float*)alloc((size_t)N_NODES * H * 4);
    float* aggx  = (float*)alloc((size_t)N_NODES * 3 * 4);
    bf16*  ea_bf = (bf16*) alloc((size_t)N_EDGES * 2 * 2);
    bf16*  e_w1t = (bf16*) alloc((size_t)2 * 128 * 288 * 2);
    bf16*  e_w2t = (bf16*) alloc((size_t)2 * 128 * 128 * 2);
    bf16*  n_w1t = (bf16*) alloc((size_t)2 * 128 * 256 * 2);
    bf16*  n_w2t = (bf16*) alloc((size_t)2 * 128 * 128 * 2);
    bf16*  c_w1t = (bf16*) alloc((size_t)128 * 288 * 2);
    bf16*  c_w2t = (bf16*) alloc((size_t)128 * 128 * 2);

    auto tp = [&](bf16* dst, const float* src, int K, int KP) {
        int tot = 128 * KP;
        transpose_pad_kernel<<<(tot + 255) / 256, 256, 0, stream>>>(dst, src, K, 128, KP);
    };
    tp(e_w1t, e_w1, 258, 288);               tp(e_w1t + 128 * 288, e_w1 + 258 * 128, 258, 288);
    tp(e_w2t, e_w2, 128, 128);               tp(e_w2t + 128 * 128, e_w2 + 128 * 128, 128, 128);
    tp(n_w1t, n_w1, 256, 256);               tp(n_w1t + 128 * 256, n_w1 + 256 * 128, 256, 256);
    tp(n_w2t, n_w2, 128, 128);               tp(n_w2t + 128 * 128, n_w2 + 128 * 128, 128, 128);
    tp(c_w1t, c_w1, 258, 288);
    tp(c_w2t, c_w2, 128, 128);

    h_init_kernel<<<(N_NODES * H + 255) / 256, 256, 0, stream>>>(h_in, h_cur, h_bf, N_NODES * H);
    ea_kernel<<<(N_EDGES + 255) / 256, 256, 0, stream>>>(x_in, ei, eattr, ea_bf);

    for (int i = 0; i < 2; ++i) {
        hipMemsetAsync(agg, 0, (size_t)N_NODES * H * 4, stream);
        edge_kernel<0><<<N_EDGES / 64, 256, 0, stream>>>(
            h_bf, ea_bf, ei, emask,
            e_w1t + (size_t)i * 128 * 288, e_b1 + i * H,
            e_w2t + (size_t)i * 128 * 128, e_b2 + i * H,
            a_w + i * H, a_b + i, nullptr, agg);
        node_kernel<<<(N_NODES + 63) / 64, 256, 0, stream>>>(
            h_cur, h_bf, agg,
            n_w1t + (size_t)i * 128 * 256, n_b1 + i * H,
            n_w2t + (size_t)i * 128 * 128, n_b2 + i * H, nmask);
    }
    hipMemsetAsync(aggx, 0, (size_t)N_NODES * 3 * 4, stream);
    edge_kernel<1><<<N_EDGES / 64, 256, 0, stream>>>(
        h_bf, ea_bf, ei, emask,
        c_w1t, c_b1, c_w2t, c_b2, c_w3, nullptr, x_in, aggx);

    out_h_kernel<<<(N_NODES * H + 255) / 256, 256, 0, stream>>>(h_cur, nmask, out);
    out_x_kernel<<<(N_NODES * 3 + 255) / 256, 256, 0, stream>>>(x_in, aggx, nmask, out + (size_t)N_NODES * H);
}

// Round 3
// 1293.143 us; speedup vs baseline: 8.6024x; 8.6024x over previous
//
#include <hip/hip_runtime.h>
#include <hip/hip_bf16.h>
#include <math.h>

#define DEV __device__ __forceinline__

typedef __bf16 bf16;
typedef bf16 bf16x8 __attribute__((ext_vector_type(8)));
typedef bf16 bf16x2 __attribute__((ext_vector_type(2)));
typedef float f32x4 __attribute__((ext_vector_type(4)));
typedef unsigned int uint;

constexpr int N_NODES = 50000;
constexpr int N_EDGES = 800000;
constexpr int H = 128;
constexpr int NB_SCAN = (N_NODES + 255) / 256;  // 196

DEV float fsilu(float x) { return x / (1.f + __expf(-x)); }
DEV float fsigmoid(float x) { return 1.f / (1.f + __expf(-x)); }

// ---------------- small prep kernels ----------------

__global__ void transpose_pad_kernel(bf16* __restrict__ dst, const float* __restrict__ src,
                                     int K, int Nf, int KP) {
    int idx = blockIdx.x * 256 + threadIdx.x;
    if (idx >= Nf * KP) return;
    int n = idx / KP, k = idx - n * KP;
    dst[idx] = (k < K) ? (bf16)src[k * Nf + n] : (bf16)0.f;
}

__global__ void h_init_kernel(const float* __restrict__ h, float* __restrict__ h_cur,
                              bf16* __restrict__ h_bf, int n) {
    int i = blockIdx.x * 256 + threadIdx.x;
    if (i < n) { float v = h[i]; h_cur[i] = v; h_bf[i] = (bf16)v; }
}

__global__ void ea_kernel(const float* __restrict__ x, const int* __restrict__ ei,
                          const float* __restrict__ eattr, bf16* __restrict__ ea_bf) {
    int e = blockIdx.x * 256 + threadIdx.x;
    if (e >= N_EDGES) return;
    int r = ei[e], c = ei[N_EDGES + e];
    float dx = x[r * 3 + 0] - x[c * 3 + 0];
    float dy = x[r * 3 + 1] - x[c * 3 + 1];
    float dz = x[r * 3 + 2] - x[c * 3 + 2];
    float radial = dx * dx + dy * dy + dz * dz;
    ea_bf[e * 2 + 0] = (bf16)radial;
    ea_bf[e * 2 + 1] = (bf16)eattr[e];
}

__global__ void out_h_kernel(const float* __restrict__ h_cur, const float* __restrict__ nmask,
                             float* __restrict__ out) {
    int i = blockIdx.x * 256 + threadIdx.x;
    if (i < N_NODES * H) out[i] = h_cur[i] * nmask[i >> 7];
}

// ---------------- CSR build (group edges by row) ----------------

__global__ void count_kernel(const int* __restrict__ ei, int* __restrict__ deg) {
    int e = blockIdx.x * 256 + threadIdx.x;
    if (e < N_EDGES) atomicAdd(&deg[ei[e]], 1);
}

__global__ void scan1_kernel(const int* __restrict__ deg, int* __restrict__ off,
                             int* __restrict__ bsum) {
    __shared__ int s[256];
    int t = threadIdx.x, i = blockIdx.x * 256 + t;
    int v = (i < N_NODES) ? deg[i] : 0;
    s[t] = v;
    __syncthreads();
#pragma unroll
    for (int st = 1; st < 256; st <<= 1) {
        int x = (t >= st) ? s[t - st] : 0;
        __syncthreads();
        s[t] += x;
        __syncthreads();
    }
    if (i < N_NODES) off[i] = s[t] - v;           // exclusive within block
    if (t == 255) bsum[blockIdx.x] = s[255];      // block total
}

__global__ void scan2_kernel(int* __restrict__ bsum) {
    __shared__ int s[256];
    int t = threadIdx.x;
    int v = (t < NB_SCAN) ? bsum[t] : 0;
    s[t] = v;
    __syncthreads();
#pragma unroll
    for (int st = 1; st < 256; st <<= 1) {
        int x = (t >= st) ? s[t - st] : 0;
        __syncthreads();
        s[t] += x;
        __syncthreads();
    }
    if (t < NB_SCAN) bsum[t] = s[t] - v;          // exclusive
}

__global__ void scan3_kernel(int* __restrict__ off, int* __restrict__ cursor,
                             const int* __restrict__ bsum) {
    int i = blockIdx.x * 256 + threadIdx.x;
    if (i >= N_NODES) return;
    int o = off[i] + bsum[blockIdx.x];
    off[i] = o;
    cursor[i] = o;
}

__global__ void fill_kernel(const int* __restrict__ ei, int* __restrict__ cursor,
                            int* __restrict__ eids) {
    int e = blockIdx.x * 256 + threadIdx.x;
    if (e >= N_EDGES) return;
    int slot = atomicAdd(&cursor[ei[e]], 1);
    eids[slot] = e;
}

// ---------------- gathers ----------------

// agg_bf[n][:] = bf16( sum_{e in row(n)} ef[e][:] * 0.01 ) ; 1 wave/node, lane = 2 feats
__global__ __launch_bounds__(256) void gather_h_kernel(
    const bf16* __restrict__ ef, const int* __restrict__ off, const int* __restrict__ deg,
    const int* __restrict__ eids, bf16* __restrict__ agg_bf) {
    int t = threadIdx.x, lane = t & 63, wv = t >> 6;
    int n = blockIdx.x * 4 + wv;
    if (n >= N_NODES) return;
    int st = off[n], dg = deg[n];
    float s0 = 0.f, s1 = 0.f;
    for (int k = 0; k < dg; ++k) {
        int e = eids[st + k];
        uint v = *(const uint*)(ef + (size_t)e * H + lane * 2);
        s0 += __uint_as_float(v << 16);
        s1 += __uint_as_float(v & 0xffff0000u);
    }
    bf16x2 o;
    o[0] = (bf16)(s0 * 0.01f);
    o[1] = (bf16)(s1 * 0.01f);
    *(bf16x2*)(agg_bf + (size_t)n * H + lane * 2) = o;
}

// out_x[n] = (x[n] + sum_{e in row(n)} trans[e] * 0.01) * nmask[n] ; 1 wave/node
__global__ __launch_bounds__(256) void gather_x_kernel(
    const float* __restrict__ trans, const int* __restrict__ off, const int* __restrict__ deg,
    const int* __restrict__ eids, const float* __restrict__ x, const float* __restrict__ nmask,
    float* __restrict__ outx) {
    int t = threadIdx.x, lane = t & 63, wv = t >> 6;
    int n = blockIdx.x * 4 + wv;
    if (n >= N_NODES) return;
    int st = off[n], dg = deg[n];
    float sx = 0.f, sy = 0.f, sz = 0.f;
    for (int k = lane; k < dg; k += 64) {
        int e = eids[st + k];
        sx += trans[e * 3 + 0];
        sy += trans[e * 3 + 1];
        sz += trans[e * 3 + 2];
    }
#pragma unroll
    for (int m = 1; m < 64; m <<= 1) {
        sx += __shfl_xor(sx, m);
        sy += __shfl_xor(sy, m);
        sz += __shfl_xor(sz, m);
    }
    if (lane == 0) {
        float nm = nmask[n];
        outx[n * 3 + 0] = (x[n * 3 + 0] + sx * 0.01f) * nm;
        outx[n * 3 + 1] = (x[n * 3 + 1] + sy * 0.01f) * nm;
        outx[n * 3 + 2] = (x[n * 3 + 2] + sz * 0.01f) * nm;
    }
}

// ---------------- MFMA helpers ----------------
// A layout (16x16x32 bf16): lane holds A[lane&15][(lane>>4)*8 + i]
// C/D layout (HW-verified): col = lane&15, row = (lane>>4)*4 + reg

template <int KCHUNKS, int ASTRIDE, int BSTRIDE>
DEV void wave_gemm(const bf16* A_lds, const bf16* __restrict__ Bt,
                   f32x4 (&acc)[4][2], int lr, int lg, int wv) {
#pragma unroll
    for (int kk = 0; kk < KCHUNKS; ++kk) {
        int ko = kk * 32 + lg * 8;
        bf16x8 a[4], b[2];
#pragma unroll
        for (int er = 0; er < 4; ++er)
            a[er] = *(const bf16x8*)(A_lds + (er * 16 + lr) * ASTRIDE + ko);
#pragma unroll
        for (int j = 0; j < 2; ++j)
            b[j] = *(const bf16x8*)(Bt + (size_t)((wv * 2 + j) * 16 + lr) * BSTRIDE + ko);
#pragma unroll
        for (int er = 0; er < 4; ++er)
#pragma unroll
            for (int j = 0; j < 2; ++j)
                acc[er][j] = __builtin_amdgcn_mfma_f32_16x16x32_bf16(a[er], b[j], acc[er][j], 0, 0, 0);
    }
}

DEV void epi_silu_store(const f32x4 (&acc)[4][2], const float* __restrict__ bias,
                        bf16* out_lds, int OSTRIDE, int lr, int lg, int wv) {
    float b0 = bias[(wv * 2 + 0) * 16 + lr];
    float b1 = bias[(wv * 2 + 1) * 16 + lr];
#pragma unroll
    for (int er = 0; er < 4; ++er) {
#pragma unroll
        for (int j = 0; j < 2; ++j) {
            float bb = j ? b1 : b0;
            int fcol = (wv * 2 + j) * 16 + lr;
#pragma unroll
            for (int r = 0; r < 4; ++r) {
                int rrow = er * 16 + lg * 4 + r;
                out_lds[rrow * OSTRIDE + fcol] = (bf16)fsilu(acc[er][j][r] + bb);
            }
        }
    }
}

// ---------------- edge / coord kernel ----------------
// MODE 0: GCL edge MLP + attention -> ef[e][128] bf16 (coalesced store, no atomics)
// MODE 1: coord MLP -> phi -> trans[e][3] f32
template <int MODE>
__global__ __launch_bounds__(256, 2) void edge_kernel(
    const bf16* __restrict__ h_bf, const bf16* __restrict__ ea_bf,
    const int* __restrict__ ei, const float* __restrict__ emask,
    const bf16* __restrict__ w1t, const float* __restrict__ b1,
    const bf16* __restrict__ w2t, const float* __restrict__ b2,
    const float* __restrict__ avec, const float* __restrict__ abias,
    const float* __restrict__ xg, bf16* __restrict__ efout, float* __restrict__ trans) {
    constexpr int SR1 = 296;
    constexpr int TR = 136;
    __shared__ __align__(16) bf16 einp[64 * SR1];  // reused as mij [64][TR]
    __shared__ __align__(16) bf16 t1[64 * TR];
    __shared__ int row_l[64];
    __shared__ int col_l[64];
    __shared__ float em_l[64];

    int t = threadIdx.x, lane = t & 63, wv = t >> 6;
    int lr = lane & 15, lg = lane >> 4;
    int ebase = blockIdx.x * 64;

    if (t < 64) {
        int e = ebase + t;
        row_l[t] = ei[e];
        col_l[t] = ei[N_EDGES + e];
        em_l[t] = emask[e];
        einp[t * SR1 + 256] = ea_bf[e * 2 + 0];
        einp[t * SR1 + 257] = ea_bf[e * 2 + 1];
#pragma unroll
        for (int k = 258; k < 288; ++k) einp[t * SR1 + k] = (bf16)0.f;
    }
    {
        int el = t >> 2, q = t & 3;
        int e = ebase + el;
        int rr = ei[e], cc = ei[N_EDGES + e];
        const bf16* hr = h_bf + (size_t)rr * H;
        const bf16* hc = h_bf + (size_t)cc * H;
        bf16* dst = einp + el * SR1;
#pragma unroll
        for (int pp = 0; pp < 4; ++pp) {
            int ch = pp * 4 + q;
            *(bf16x8*)(dst + ch * 8) = *(const bf16x8*)(hr + ch * 8);
            *(bf16x8*)(dst + 128 + ch * 8) = *(const bf16x8*)(hc + ch * 8);
        }
    }
    __syncthreads();

    f32x4 acc[4][2];
#pragma unroll
    for (int er = 0; er < 4; ++er)
#pragma unroll
        for (int j = 0; j < 2; ++j) acc[er][j] = (f32x4)0.f;
    wave_gemm<9, SR1, 288>(einp, w1t, acc, lr, lg, wv);
    epi_silu_store(acc, b1, t1, TR, lr, lg, wv);
    __syncthreads();

    f32x4 acc2[4][2];
#pragma unroll
    for (int er = 0; er < 4; ++er)
#pragma unroll
        for (int j = 0; j < 2; ++j) acc2[er][j] = (f32x4)0.f;
    wave_gemm<4, TR, 128>(t1, w2t, acc2, lr, lg, wv);

    bf16* mij = einp;  // reuse einp region
    epi_silu_store(acc2, b2, mij, TR, lr, lg, wv);
    __syncthreads();

    // per-edge dot over 128 feats: 4 threads/edge, shfl reduce
    int el = t >> 2, q = t & 3;
    const bf16* mrow = mij + el * TR + q * 32;
    float part = 0.f;
#pragma unroll
    for (int c = 0; c < 4; ++c) {
        bf16x8 v = *(const bf16x8*)(mrow + c * 8);
#pragma unroll
        for (int jj = 0; jj < 8; ++jj) part += (float)v[jj] * avec[q * 32 + c * 8 + jj];
    }
    part += __shfl_xor(part, 1);
    part += __shfl_xor(part, 2);

    if (MODE == 0) {
        float att = fsigmoid(part + abias[0]);
        float scale = att * em_l[el];
        bf16* edst = efout + (size_t)(ebase + el) * H + q * 32;
#pragma unroll
        for (int c = 0; c < 4; ++c) {
            bf16x8 v = *(const bf16x8*)(mrow + c * 8);
            bf16x8 o;
#pragma unroll
            for (int jj = 0; jj < 8; ++jj) o[jj] = (bf16)((float)v[jj] * scale);
            *(bf16x8*)(edst + c * 8) = o;
        }
    } else {
        if (q == 0) {
            int rr = row_l[el], cc = col_l[el];
            float dx = xg[rr * 3 + 0] - xg[cc * 3 + 0];
            float dy = xg[rr * 3 + 1] - xg[cc * 3 + 1];
            float dz = xg[rr * 3 + 2] - xg[cc * 3 + 2];
            float radial = dx * dx + dy * dy + dz * dz;
            float inv = 1.f / (sqrtf(radial + 1e-8f) + 1.f);
            float s = part * em_l[el] * inv;
            int e = ebase + el;
            trans[e * 3 + 0] = dx * s;
            trans[e * 3 + 1] = dy * s;
            trans[e * 3 + 2] = dz * s;
        }
    }
}

// ---------------- node MLP kernel ----------------
__global__ __launch_bounds__(256, 2) void node_kernel(
    float* __restrict__ h_cur, bf16* __restrict__ h_bf, const bf16* __restrict__ agg_bf,
    const bf16* __restrict__ w1t, const float* __restrict__ b1,
    const bf16* __restrict__ w2t, const float* __restrict__ b2,
    const float* __restrict__ nmask) {
    constexpr int SRN = 264;
    constexpr int TRN = 136;
    __shared__ __align__(16) bf16 ninp[64 * SRN];
    __shared__ __align__(16) bf16 t1[64 * TRN];

    int t = threadIdx.x, lane = t & 63, wv = t >> 6;
    int lr = lane & 15, lg = lane >> 4;
    int nbase = blockIdx.x * 64;

    {   // stage ninp = [bf16(h), agg_bf]
        int nl = t >> 2, q = t & 3;
        int node = nbase + nl;
        bf16* dst = ninp + nl * SRN;
        if (node < N_NODES) {
            const float4* hr = (const float4*)(h_cur + (size_t)node * H);
            const bf16* ar = agg_bf + (size_t)node * H;
#pragma unroll
            for (int pp = 0; pp < 8; ++pp) {
                int ch = pp * 4 + q;
                float4 v = hr[ch];
                dst[ch * 4 + 0] = (bf16)v.x; dst[ch * 4 + 1] = (bf16)v.y;
                dst[ch * 4 + 2] = (bf16)v.z; dst[ch * 4 + 3] = (bf16)v.w;
            }
#pragma unroll
            for (int pp = 0; pp < 4; ++pp) {
                int ch = pp * 4 + q;
                *(bf16x8*)(dst + 128 + ch * 8) = *(const bf16x8*)(ar + ch * 8);
            }
        } else {
#pragma unroll
            for (int pp = 0; pp < 8; ++pp) {
                int ch = pp * 4 + q;
#pragma unroll
                for (int k = 0; k < 4; ++k) {
                    dst[ch * 4 + k] = (bf16)0.f;
                    dst[128 + ch * 4 + k] = (bf16)0.f;
                }
            }
        }
    }
    __syncthreads();

    f32x4 acc[4][2];
#pragma unroll
    for (int er = 0; er < 4; ++er)
#pragma unroll
        for (int j = 0; j < 2; ++j) acc[er][j] = (f32x4)0.f;
    wave_gemm<8, SRN, 256>(ninp, w1t, acc, lr, lg, wv);
    epi_silu_store(acc, b1, t1, TRN, lr, lg, wv);
    __syncthreads();

    f32x4 acc2[4][2];
#pragma unroll
    for (int er = 0; er < 4; ++er)
#pragma unroll
        for (int j = 0; j < 2; ++j) acc2[er][j] = (f32x4)0.f;
    wave_gemm<4, TRN, 128>(t1, w2t, acc2, lr, lg, wv);

    float bb0 = b2[(wv * 2 + 0) * 16 + lr];
    float bb1 = b2[(wv * 2 + 1) * 16 + lr];
#pragma unroll
    for (int er = 0; er < 4; ++er) {
#pragma unroll
        for (int j = 0; j < 2; ++j) {
            float bb = j ? bb1 : bb0;
            int feat = (wv * 2 + j) * 16 + lr;
#pragma unroll
            for (int r = 0; r < 4; ++r) {
                int node = nbase + er * 16 + lg * 4 + r;
                if (node < N_NODES) {
                    size_t idx = (size_t)node * H + feat;
                    float nm = nmask[node];
                    float v = (h_cur[idx] + acc2[er][j][r] + bb) * nm;  // fp32 residual
                    h_cur[idx] = v;
                    h_bf[idx] = (bf16)v;
                }
            }
        }
    }
}

// ---------------- launch ----------------
extern "C" void kernel_launch(void* const* d_in, const int* in_sizes, int n_in,
                              void* d_out, int out_size, void* d_ws, size_t ws_size,
                              hipStream_t stream) {
    (void)in_sizes; (void)n_in; (void)out_size; (void)ws_size;
    const float* h_in  = (const float*)d_in[0];
    const float* x_in  = (const float*)d_in[1];
    const int*   ei    = (const int*)d_in[2];
    const float* eattr = (const float*)d_in[3];
    const float* nmask = (const float*)d_in[4];
    const float* emask = (const float*)d_in[5];
    const float* e_w1  = (const float*)d_in[6];
    const float* e_b1  = (const float*)d_in[7];
    const float* e_w2  = (const float*)d_in[8];
    const float* e_b2  = (const float*)d_in[9];
    const float* a_w   = (const float*)d_in[10];
    const float* a_b   = (const float*)d_in[11];
    const float* n_w1  = (const float*)d_in[12];
    const float* n_b1  = (const float*)d_in[13];
    const float* n_w2  = (const float*)d_in[14];
    const float* n_b2  = (const float*)d_in[15];
    const float* c_w1  = (const float*)d_in[16];
    const float* c_b1  = (const float*)d_in[17];
    const float* c_w2  = (const float*)d_in[18];
    const float* c_b2  = (const float*)d_in[19];
    const float* c_w3  = (const float*)d_in[20];
    float* out = (float*)d_out;

    char* p = (char*)d_ws;
    auto alloc = [&](size_t bytes) { char* r = p; p += (bytes + 255) & ~(size_t)255; return r; };
    float* h_cur  = (float*)alloc((size_t)N_NODES * H * 4);
    bf16*  h_bf   = (bf16*) alloc((size_t)N_NODES * H * 2);
    bf16*  agg_bf = (bf16*) alloc((size_t)N_NODES * H * 2);
    bf16*  ea_bf  = (bf16*) alloc((size_t)N_EDGES * 2 * 2);
    bf16*  ef     = (bf16*) alloc((size_t)N_EDGES * H * 2);   // big: 204.8 MB
    float* trans  = (float*)ef;                               // alias: ef dead before edge<1>
    int*   deg    = (int*)  alloc((size_t)N_NODES * 4);
    int*   off    = (int*)  alloc((size_t)N_NODES * 4);
    int*   cursor = (int*)  alloc((size_t)N_NODES * 4);
    int*   bsum   = (int*)  alloc((size_t)NB_SCAN * 4);
    int*   eids   = (int*)  alloc((size_t)N_EDGES * 4);
    bf16*  e_w1t  = (bf16*) alloc((size_t)2 * 128 * 288 * 2);
    bf16*  e_w2t  = (bf16*) alloc((size_t)2 * 128 * 128 * 2);
    bf16*  n_w1t  = (bf16*) alloc((size_t)2 * 128 * 256 * 2);
    bf16*  n_w2t  = (bf16*) alloc((size_t)2 * 128 * 128 * 2);
    bf16*  c_w1t  = (bf16*) alloc((size_t)128 * 288 * 2);
    bf16*  c_w2t  = (bf16*) alloc((size_t)128 * 128 * 2);

    auto tp = [&](bf16* dst, const float* src, int K, int KP) {
        int tot = 128 * KP;
        transpose_pad_kernel<<<(tot + 255) / 256, 256, 0, stream>>>(dst, src, K, 128, KP);
    };
    tp(e_w1t, e_w1, 258, 288);               tp(e_w1t + 128 * 288, e_w1 + 258 * 128, 258, 288);
    tp(e_w2t, e_w2, 128, 128);               tp(e_w2t + 128 * 128, e_w2 + 128 * 128, 128, 128);
    tp(n_w1t, n_w1, 256, 256);               tp(n_w1t + 128 * 256, n_w1 + 256 * 128, 256, 256);
    tp(n_w2t, n_w2, 128, 128);               tp(n_w2t + 128 * 128, n_w2 + 128 * 128, 128, 128);
    tp(c_w1t, c_w1, 258, 288);
    tp(c_w2t, c_w2, 128, 128);

    h_init_kernel<<<(N_NODES * H + 255) / 256, 256, 0, stream>>>(h_in, h_cur, h_bf, N_NODES * H);
    ea_kernel<<<(N_EDGES + 255) / 256, 256, 0, stream>>>(x_in, ei, eattr, ea_bf);

    // ---- CSR build ----
    hipMemsetAsync(deg, 0, (size_t)N_NODES * 4, stream);
    count_kernel<<<(N_EDGES + 255) / 256, 256, 0, stream>>>(ei, deg);
    scan1_kernel<<<NB_SCAN, 256, 0, stream>>>(deg, off, bsum);
    scan2_kernel<<<1, 256, 0, stream>>>(bsum);
    scan3_kernel<<<NB_SCAN, 256, 0, stream>>>(off, cursor, bsum);
    fill_kernel<<<(N_EDGES + 255) / 256, 256, 0, stream>>>(ei, cursor, eids);

    int ngrid = (N_NODES + 3) / 4;
    for (int i = 0; i < 2; ++i) {
        edge_kernel<0><<<N_EDGES / 64, 256, 0, stream>>>(
            h_bf, ea_bf, ei, emask,
            e_w1t + (size_t)i * 128 * 288, e_b1 + i * H,
            e_w2t + (size_t)i * 128 * 128, e_b2 + i * H,
            a_w + i * H, a_b + i, nullptr, ef, nullptr);
        gather_h_kernel<<<ngrid, 256, 0, stream>>>(ef, off, deg, eids, agg_bf);
        node_kernel<<<(N_NODES + 63) / 64, 256, 0, stream>>>(
            h_cur, h_bf, agg_bf,
            n_w1t + (size_t)i * 128 * 256, n_b1 + i * H,
            n_w2t + (size_t)i * 128 * 128, n_b2 + i * H, nmask);
    }
    edge_kernel<1><<<N_EDGES / 64, 256, 0, stream>>>(
        h_bf, ea_bf, ei, emask,
        c_w1t, c_b1, c_w2t, c_b2, c_w3, nullptr, x_in, nullptr, trans);
    gather_x_kernel<<<ngrid, 256, 0, stream>>>(trans, off, deg, eids, x_in, nmask,
                                               out + (size_t)N_NODES * H);

    out_h_kernel<<<(N_NODES * H + 255) / 256, 256, 0, stream>>>(h_cur, nmask, out);
}